// Round 3
// baseline (999.039 us; speedup 1.0000x reference)
//
#include <hip/hip_runtime.h>

// Butterfly multiply, B=16384, N=2048, LOG_N=11, increasing stride.
// Compute layout (validated in R1): e = lane*32 + r  (r = register 0..31).
//   stages 0..4  (s=1..16)   : pair in-register (r bits)
//   stages 5..10 (s=32..1024): pair across lanes -> __shfl_xor
// Global I/O fix vs R1: coalesced float4 through a per-wave LDS transpose
// buffer (pad +1 float per 32 -> bank = (lane+r)%32, 2-way only = free).
// twiddle flat: st*4096 + p*4 + i*2 + j, p = ((e>>(st+1))<<st) | (e & (s-1)).

constexpr int BATCH = 16384;
constexpr int N = 2048;
constexpr int REGS = 32;            // elements per lane per row
constexpr int ROWS = 4;             // rows per wave (twiddle reuse)
constexpr int WPB = 4;              // waves per block
constexpr int BLOCK = 64 * WPB;
constexpr int LDSF = N + N / 32;    // 2112 floats per wave buffer (padded)

__global__ __launch_bounds__(BLOCK, 2)
void butterfly_kernel(const float* __restrict__ x,
                      const float* __restrict__ tw,
                      const float* __restrict__ bias,
                      float* __restrict__ out)
{
    __shared__ float lds[WPB * LDSF];        // 33792 B
    const int lane = threadIdx.x & 63;
    const int wv   = threadIdx.x >> 6;
    float* buf = lds + wv * LDSF;            // per-wave private buffer
    const int wid  = blockIdx.x * WPB + wv;
    const size_t row0 = (size_t)wid * ROWS;

    float v[ROWS][REGS];

    // ---- Phase 1: coalesced global load -> LDS -> transposed registers
    for (int rr = 0; rr < ROWS; ++rr) {
        const float* src = x + (row0 + rr) * N;
        float4 f[8];
        #pragma unroll
        for (int t = 0; t < 8; ++t)
            f[t] = *(const float4*)(src + t * 256 + 4 * lane);
        __syncthreads();                     // prior row's LDS reads done
        #pragma unroll
        for (int t = 0; t < 8; ++t) {
            const int e0  = t * 256 + 4 * lane;
            const int idx = e0 + (e0 >> 5);  // pad; j=0..3 never crosses a pad
            buf[idx + 0] = f[t].x; buf[idx + 1] = f[t].y;
            buf[idx + 2] = f[t].z; buf[idx + 3] = f[t].w;
        }
        __syncthreads();
        #pragma unroll
        for (int r = 0; r < REGS; ++r)
            v[rr][r] = buf[lane * 33 + r];   // bank (lane+r)%32: 2-way, free
    }

    // ---- stages 0..4 (s = 1..16): both pair halves within the lane
    #pragma unroll
    for (int st = 0; st < 5; ++st) {
        const int s = 1 << st;
        const float* twst = tw + (st << 12);
        #pragma unroll
        for (int r = 0; r < REGS; ++r) {
            if (r & s) continue;             // visit each pair once (at lo)
            const int e = lane * REGS + r;
            const int p = ((e >> (st + 1)) << st) | (e & (s - 1));
            const float4 t4 = *(const float4*)(twst + 4 * p);
            #pragma unroll
            for (int rr = 0; rr < ROWS; ++rr) {
                const float lo = v[rr][r];
                const float hi = v[rr][r + s];
                v[rr][r]     = fmaf(t4.x, lo, t4.y * hi);
                v[rr][r + s] = fmaf(t4.z, lo, t4.w * hi);
            }
        }
    }

    // ---- stages 5..10 (s = 32..1024): partner in lane ^ m, same register
    #pragma unroll
    for (int st = 5; st < 11; ++st) {
        const int m = 1 << (st - 5);
        const int hiHalf = (lane >> (st - 5)) & 1;
        const float* twst = tw + (st << 12);
        #pragma unroll
        for (int r = 0; r < REGS; ++r) {
            const int e = lane * REGS + r;
            const int p = ((e >> (st + 1)) << st) | (e & ((1 << st) - 1));
            const float2 t2 = *(const float2*)(twst + 4 * p + 2 * hiHalf);
            #pragma unroll
            for (int rr = 0; rr < ROWS; ++rr) {
                const float mine = v[rr][r];
                const float part = __shfl_xor(mine, m, 64);
                const float lo = hiHalf ? part : mine;
                const float hi = hiHalf ? mine : part;
                v[rr][r] = fmaf(t2.x, lo, t2.y * hi);
            }
        }
    }

    // ---- Phase 3: registers -> LDS -> coalesced store with bias
    for (int rr = 0; rr < ROWS; ++rr) {
        __syncthreads();                     // prior row's coalesced reads done
        #pragma unroll
        for (int r = 0; r < REGS; ++r)
            buf[lane * 33 + r] = v[rr][r];
        __syncthreads();
        float* dst = out + (row0 + rr) * N;
        #pragma unroll
        for (int t = 0; t < 8; ++t) {
            const int e0  = t * 256 + 4 * lane;
            const int idx = e0 + (e0 >> 5);
            const float4 b = *(const float4*)(bias + e0);
            float4 o;
            o.x = buf[idx + 0] + b.x;
            o.y = buf[idx + 1] + b.y;
            o.z = buf[idx + 2] + b.z;
            o.w = buf[idx + 3] + b.w;
            *(float4*)(dst + e0) = o;
        }
    }
}

extern "C" void kernel_launch(void* const* d_in, const int* in_sizes, int n_in,
                              void* d_out, int out_size, void* d_ws, size_t ws_size,
                              hipStream_t stream) {
    const float* x    = (const float*)d_in[0];
    const float* tw   = (const float*)d_in[1];
    const float* bias = (const float*)d_in[2];
    float* out = (float*)d_out;

    const int total_waves = BATCH / ROWS;        // 4096 waves
    const int grid = total_waves / WPB;          // 1024 blocks
    butterfly_kernel<<<grid, BLOCK, 0, stream>>>(x, tw, bias, out);
}

// Round 4
// 712.133 us; speedup vs baseline: 1.4029x; 1.4029x over previous
//
#include <hip/hip_runtime.h>

// Butterfly multiply, B=16384, N=2048, LOG_N=11, increasing stride.
// Element layout: e = r*128 + lane*2 + j   (r in [0,16), j in {0,1})
// Register k = 2*r + j. All global I/O AND twiddle loads are coalesced
// (lane occupies low bits of e, so per-lane addresses advance with lane).
//   stage 0      (s=1)        : pair = j bit, in-lane, float4 twiddle
//   stages 1..6  (s=2..64)    : pair = lane bit (st-1) -> __shfl_xor
//   stages 7..10 (s=128..1024): pair = r bit (st-7), in-register
// Pair index p = ((e>>(st+1))<<st) | (e & (s-1)); twiddle flat offset
// st*4096 + 4*p + 2*i + jj  (floats).
// ROWS=2 keeps v[][] at 64 VGPRs -> no scratch spill (R1/R3 lesson:
// VGPR_Count=128 + ROWS=4 spilled ~1.7 GB of scratch traffic to HBM).

constexpr int BATCH = 16384;
constexpr int N = 2048;
constexpr int ROWS = 2;             // rows per wave (twiddle reuse vs regs)
constexpr int WPB = 4;              // waves per block
constexpr int BLOCK = 64 * WPB;

__global__ __launch_bounds__(BLOCK, 2)
void butterfly_kernel(const float* __restrict__ x,
                      const float* __restrict__ tw,
                      const float* __restrict__ bias,
                      float* __restrict__ out)
{
    const int lane = threadIdx.x & 63;
    const int wid  = blockIdx.x * WPB + (threadIdx.x >> 6);
    const size_t row0 = (size_t)wid * ROWS;
    const int l2 = lane * 2;

    float v[ROWS][32];

    // ---- coalesced float2 loads (512 B per wave-inst)
    #pragma unroll
    for (int rr = 0; rr < ROWS; ++rr) {
        const float* src = x + (row0 + rr) * N + l2;
        #pragma unroll
        for (int r = 0; r < 16; ++r) {
            const float2 f = *(const float2*)(src + r * 128);
            v[rr][2*r]   = f.x;
            v[rr][2*r+1] = f.y;
        }
    }

    // ---- stage 0 (s=1): in-lane pair (j bit), coalesced float4 twiddle
    #pragma unroll 4
    for (int r = 0; r < 16; ++r) {
        const int p = r * 64 + lane;
        const float4 t4 = *(const float4*)(tw + 4 * p);
        #pragma unroll
        for (int rr = 0; rr < ROWS; ++rr) {
            const float lo = v[rr][2*r];
            const float hi = v[rr][2*r+1];
            v[rr][2*r]   = fmaf(t4.x, lo, t4.y * hi);
            v[rr][2*r+1] = fmaf(t4.z, lo, t4.w * hi);
        }
    }

    // ---- stages 1..6 (s=2..64): cross-lane via __shfl_xor
    #pragma unroll
    for (int st = 1; st < 7; ++st) {
        const int s = 1 << st;
        const int m = 1 << (st - 1);              // lane xor mask
        const int hiHalf = (lane >> (st - 1)) & 1;
        const float* twst = tw + (st << 12);
        #pragma unroll 8
        for (int k = 0; k < 32; ++k) {
            const int e = (k >> 1) * 128 + l2 + (k & 1);
            const int p = ((e >> (st + 1)) << st) | (e & (s - 1));
            const float2 t2 = *(const float2*)(twst + 4 * p + 2 * hiHalf);
            #pragma unroll
            for (int rr = 0; rr < ROWS; ++rr) {
                const float mine = v[rr][k];
                const float part = __shfl_xor(mine, m, 64);
                const float lo = hiHalf ? part : mine;
                const float hi = hiHalf ? mine : part;
                v[rr][k] = fmaf(t2.x, lo, t2.y * hi);
            }
        }
    }

    // ---- stages 7..10 (s=128..1024): in-register (r bit st-7)
    #pragma unroll
    for (int st = 7; st < 11; ++st) {
        const int s = 1 << st;
        const int rm = 1 << (st - 7);
        const float* twst = tw + (st << 12);
        #pragma unroll 4
        for (int r = 0; r < 16; ++r) {
            if (r & rm) continue;                  // visit each pair at lo
            #pragma unroll
            for (int j = 0; j < 2; ++j) {
                const int e = r * 128 + l2 + j;
                const int p = ((e >> (st + 1)) << st) | (e & (s - 1));
                const float4 t4 = *(const float4*)(twst + 4 * p);
                const int klo = 2 * r + j;
                const int khi = 2 * (r + rm) + j;
                #pragma unroll
                for (int rr = 0; rr < ROWS; ++rr) {
                    const float lo = v[rr][klo];
                    const float hi = v[rr][khi];
                    v[rr][klo] = fmaf(t4.x, lo, t4.y * hi);
                    v[rr][khi] = fmaf(t4.z, lo, t4.w * hi);
                }
            }
        }
    }

    // ---- coalesced float2 stores with bias (bias loaded once per r)
    #pragma unroll
    for (int r = 0; r < 16; ++r) {
        const float2 b = *(const float2*)(bias + r * 128 + l2);
        #pragma unroll
        for (int rr = 0; rr < ROWS; ++rr) {
            float2 o;
            o.x = v[rr][2*r]   + b.x;
            o.y = v[rr][2*r+1] + b.y;
            *(float2*)(out + (row0 + rr) * N + r * 128 + l2) = o;
        }
    }
}

extern "C" void kernel_launch(void* const* d_in, const int* in_sizes, int n_in,
                              void* d_out, int out_size, void* d_ws, size_t ws_size,
                              hipStream_t stream) {
    const float* x    = (const float*)d_in[0];
    const float* tw   = (const float*)d_in[1];
    const float* bias = (const float*)d_in[2];
    float* out = (float*)d_out;

    const int rows_per_block = ROWS * WPB;           // 8
    const int grid = BATCH / rows_per_block;         // 2048 blocks
    butterfly_kernel<<<grid, BLOCK, 0, stream>>>(x, tw, bias, out);
}

// Round 5
// 296.084 us; speedup vs baseline: 3.3742x; 2.4052x over previous
//
#include <hip/hip_runtime.h>

// Butterfly multiply, B=16384, N=2048, LOG_N=11, increasing stride.
// Element layout: e = r*128 + lane*2 + j   (r in [0,16), j in {0,1})
// Register k = 2*r + j. Global I/O and twiddle loads coalesced (lane in
// low bits of e). Stage st (s=2^st), p = ((e>>(st+1))<<st) | (e & (s-1)),
// twiddle flat: st*4096 + 4*p + 2*i + jj.
//   stage 0      (s=1)        : pair = j bit, in-lane, float4 twiddle
//   stages 1..6  (s=2..64)    : pair = lane bit (st-1) -> __shfl_xor
//   stages 7..10 (s=128..1024): pair = r bit (st-7), in-register
//
// CRITICAL (R4 lesson): every loop must be FULLY unrolled. Partial unroll
// (#pragma unroll 8) left v[][] dynamically indexed -> scratch allocation
// (VGPR_Count=48, 1.5 GB spill writes). All indices below are compile-time.
// ROWS=2 keeps data at 64 VGPRs so data+temps fit even a 128-VGPR budget.

constexpr int BATCH = 16384;
constexpr int N = 2048;
constexpr int ROWS = 2;             // rows per wave (twiddle reuse vs regs)
constexpr int WPB = 4;              // waves per block
constexpr int BLOCK = 64 * WPB;

__global__ __launch_bounds__(BLOCK, 2)
void butterfly_kernel(const float* __restrict__ x,
                      const float* __restrict__ tw,
                      const float* __restrict__ bias,
                      float* __restrict__ out)
{
    const int lane = threadIdx.x & 63;
    const int wid  = blockIdx.x * WPB + (threadIdx.x >> 6);
    const size_t row0 = (size_t)wid * ROWS;
    const int l2 = lane * 2;

    float v[ROWS][32];

    // ---- coalesced float2 loads (512 B per wave-inst)
    #pragma unroll
    for (int rr = 0; rr < ROWS; ++rr) {
        const float* src = x + (row0 + rr) * N + l2;
        #pragma unroll
        for (int r = 0; r < 16; ++r) {
            const float2 f = *(const float2*)(src + r * 128);
            v[rr][2*r]   = f.x;
            v[rr][2*r+1] = f.y;
        }
    }

    // ---- stage 0 (s=1): in-lane pair (j bit), coalesced float4 twiddle
    #pragma unroll
    for (int r = 0; r < 16; ++r) {
        const int p = r * 64 + lane;
        const float4 t4 = *(const float4*)(tw + 4 * p);
        #pragma unroll
        for (int rr = 0; rr < ROWS; ++rr) {
            const float lo = v[rr][2*r];
            const float hi = v[rr][2*r+1];
            v[rr][2*r]   = fmaf(t4.x, lo, t4.y * hi);
            v[rr][2*r+1] = fmaf(t4.z, lo, t4.w * hi);
        }
    }

    // ---- stages 1..6 (s=2..64): cross-lane via __shfl_xor
    #pragma unroll
    for (int st = 1; st < 7; ++st) {
        const int s = 1 << st;
        const int m = 1 << (st - 1);              // lane xor mask
        const int hiHalf = (lane >> (st - 1)) & 1;
        const float* twst = tw + (st << 12);
        #pragma unroll
        for (int k = 0; k < 32; ++k) {
            const int e = (k >> 1) * 128 + l2 + (k & 1);
            const int p = ((e >> (st + 1)) << st) | (e & (s - 1));
            const float2 t2 = *(const float2*)(twst + 4 * p + 2 * hiHalf);
            #pragma unroll
            for (int rr = 0; rr < ROWS; ++rr) {
                const float mine = v[rr][k];
                const float part = __shfl_xor(mine, m, 64);
                const float lo = hiHalf ? part : mine;
                const float hi = hiHalf ? mine : part;
                v[rr][k] = fmaf(t2.x, lo, t2.y * hi);
            }
        }
    }

    // ---- stages 7..10 (s=128..1024): in-register (r bit st-7)
    #pragma unroll
    for (int st = 7; st < 11; ++st) {
        const int s = 1 << st;
        const int rm = 1 << (st - 7);
        const float* twst = tw + (st << 12);
        #pragma unroll
        for (int r = 0; r < 16; ++r) {
            if (r & rm) continue;                  // visit each pair at lo
            #pragma unroll
            for (int j = 0; j < 2; ++j) {
                const int e = r * 128 + l2 + j;
                const int p = ((e >> (st + 1)) << st) | (e & (s - 1));
                const float4 t4 = *(const float4*)(twst + 4 * p);
                const int klo = 2 * r + j;
                const int khi = 2 * (r + rm) + j;
                #pragma unroll
                for (int rr = 0; rr < ROWS; ++rr) {
                    const float lo = v[rr][klo];
                    const float hi = v[rr][khi];
                    v[rr][klo] = fmaf(t4.x, lo, t4.y * hi);
                    v[rr][khi] = fmaf(t4.z, lo, t4.w * hi);
                }
            }
        }
    }

    // ---- coalesced float2 stores with bias (bias loaded once per r)
    #pragma unroll
    for (int r = 0; r < 16; ++r) {
        const float2 b = *(const float2*)(bias + r * 128 + l2);
        #pragma unroll
        for (int rr = 0; rr < ROWS; ++rr) {
            float2 o;
            o.x = v[rr][2*r]   + b.x;
            o.y = v[rr][2*r+1] + b.y;
            *(float2*)(out + (row0 + rr) * N + r * 128 + l2) = o;
        }
    }
}

extern "C" void kernel_launch(void* const* d_in, const int* in_sizes, int n_in,
                              void* d_out, int out_size, void* d_ws, size_t ws_size,
                              hipStream_t stream) {
    const float* x    = (const float*)d_in[0];
    const float* tw   = (const float*)d_in[1];
    const float* bias = (const float*)d_in[2];
    float* out = (float*)d_out;

    const int rows_per_block = ROWS * WPB;           // 8
    const int grid = BATCH / rows_per_block;         // 2048 blocks
    butterfly_kernel<<<grid, BLOCK, 0, stream>>>(x, tw, bias, out);
}